// Round 18
// baseline (1047.860 us; speedup 1.0000x reference)
//
#include <hip/hip_runtime.h>

#define BATCH   8
#define NPTS    8192
#define NPOINT  1024
#define NSAMPLE 32
#define CHANC   32
#define OUTC    35          // 3 xyz + 32 point channels
#define R2      0.0625f     // 0.25^2
#define CPB     31          // consumer blocks per batch
#define NBLK    (BATCH + BATCH * CPB)   // 8 + 248 = 256
#define CTRSTRIDE 32        // ints per batch flag: one 128-B line each
#define PUBMASK 63          // publish every 64 centers

typedef float v2f __attribute__((ext_vector_type(2)));

// DPP helpers --------------------------------------------------------------
template <int CTRL>
__device__ __forceinline__ float dpp_max_step(float v) {
    int r = __builtin_amdgcn_update_dpp(__float_as_int(v), __float_as_int(v),
                                        CTRL, 0xf, 0xf, false);
    return fmaxf(v, __int_as_float(r));
}
#define DPP_ROW_SHR(n)  (0x110 | (n))
#define DPP_BCAST15     0x142
#define DPP_BCAST31     0x143

__device__ __forceinline__ unsigned long long u64max(unsigned long long a,
                                                     unsigned long long b) {
    return a > b ? a : b;
}

// agent-scope write-through store of a float (goes to device-coherent LLC,
// bypassing the non-coherent per-XCD L2 — so no release/wbl2 is needed)
__device__ __forceinline__ void agent_store_f32(float* p, float v) {
    __hip_atomic_store(p, v, __ATOMIC_RELAXED, __HIP_MEMORY_SCOPE_AGENT);
}

// ---------------------------------------------------------------------------
// Fused producer/consumer kernel, cooperative launch (256 blocks x 512 thr,
// 1 block/CU co-resident).
//  Blocks 0..7   : FROZEN r9 fps. Coord writes are agent-scope RELAXED
//                  atomic stores (write-through to LLC, fire-and-forget).
//                  Publish every 64 centers: s_waitcnt vmcnt(0) (waits only
//                  this wave's coord stores, ~600 cyc) + RELAXED agent flag
//                  store. NO release/wbl2 (r17 evidence: each release cost
//                  ~2-4 µs in XCD-L2 writeback of consumers' dirty out-lines
//                  = the remaining 67 µs over the 881 µs producer floor).
//  Blocks 8..255 : unchanged from r17: stage batch xyz in LDS, acquire-poll
//                  padded flag line (s_sleep(32)), agent atomic coord loads
//                  (LLC reads), ballot scan from LDS, coalesced gather.
// ---------------------------------------------------------------------------
__global__ __launch_bounds__(512) void fused_kernel(const float* __restrict__ xyz,
                                                    const float* __restrict__ points,
                                                    float* new_xyz,
                                                    float* out,
                                                    int* ctr) {
#pragma clang fp contract(off)
    __shared__ float4 pts[NPTS];                    // 128 KB
    __shared__ unsigned long long partial[2][8];
    __shared__ int idxbuf[8][NSAMPLE];              // consumer: per-wave

    const int blk  = blockIdx.x;
    const int t    = threadIdx.x;
    const int lane = t & 63;
    const int w    = t >> 6;

    if (blk < BATCH) {
        // ================= PRODUCER: fps for batch b =================
        const int b = blk;
        const float* bx = xyz + (size_t)b * NPTS * 3;

        v2f px[8], py[8], pz[8], dist[8];
        {
            float f[48];
            float4* fq = (float4*)f;
            const float4* s4 = (const float4*)bx + t * 12;
#pragma unroll
            for (int q = 0; q < 12; ++q) fq[q] = s4[q];
#pragma unroll
            for (int p = 0; p < 8; ++p) {
                px[p] = (v2f){f[6 * p + 0], f[6 * p + 3]};
                py[p] = (v2f){f[6 * p + 1], f[6 * p + 4]};
                pz[p] = (v2f){f[6 * p + 2], f[6 * p + 5]};
                dist[p] = (v2f){1e38f, 1e38f};
            }
#pragma unroll
            for (int i = 0; i < 16; ++i) {
                const int j  = t * 16 + i;
                const int js = j ^ ((j >> 4) & 7);      // bank swizzle
                pts[js] = make_float4(f[3 * i + 0], f[3 * i + 1], f[3 * i + 2], 0.0f);
            }
        }
        __syncthreads();

        float4 c0 = pts[0];
        float lx = c0.x, ly = c0.y, lz = c0.z;
        if (t == 0) {
            float* o = new_xyz + (size_t)b * NPOINT * 3;
            agent_store_f32(&o[0], lx);
            agent_store_f32(&o[1], ly);
            agent_store_f32(&o[2], lz);
        }

        for (int s = 1; s < NPOINT; ++s) {
            const v2f lx2 = (v2f){lx, lx};
            const v2f ly2 = (v2f){ly, ly};
            const v2f lz2 = (v2f){lz, lz};
            float bestv = -1.0f;
            int   bi    = 0;
#pragma unroll
            for (int p = 0; p < 8; ++p) {
                const v2f dx = px[p] - lx2;
                const v2f dy = py[p] - ly2;
                const v2f dz = pz[p] - lz2;
                const v2f d2 = (dx * dx + dy * dy) + dz * dz;   // contract off
                const float d0 = fminf(dist[p].x, d2.x);
                const float d1 = fminf(dist[p].y, d2.y);
                dist[p] = (v2f){d0, d1};
                if (d0 > bestv) { bestv = d0; bi = 2 * p; }
                if (d1 > bestv) { bestv = d1; bi = 2 * p + 1; }
            }
            const int besti = (t << 4) + bi;

            float v = bestv;
            v = dpp_max_step<DPP_ROW_SHR(1)>(v);
            v = dpp_max_step<DPP_ROW_SHR(2)>(v);
            v = dpp_max_step<DPP_ROW_SHR(4)>(v);
            v = dpp_max_step<DPP_ROW_SHR(8)>(v);
            v = dpp_max_step<DPP_BCAST15>(v);
            v = dpp_max_step<DPP_BCAST31>(v);
            const float smax = __int_as_float(__builtin_amdgcn_readlane(__float_as_int(v), 63));

            const unsigned long long m = __ballot(bestv == smax);
            const int par = s & 1;
            if (lane == (int)__builtin_ctzll(m)) {
                partial[par][w] = ((unsigned long long)__float_as_uint(smax) << 32)
                                  | (unsigned)(~besti);
            }
            __syncthreads();

            const unsigned long long* P = partial[par];
            const unsigned long long a0 = P[0], a1 = P[1], a2 = P[2], a3 = P[3];
            const unsigned long long a4 = P[4], a5 = P[5], a6 = P[6], a7 = P[7];
            const unsigned long long bp =
                u64max(u64max(u64max(a0, a1), u64max(a2, a3)),
                       u64max(u64max(a4, a5), u64max(a6, a7)));
            const int idx = (int)(~(unsigned)bp);
            const int js  = idx ^ ((idx >> 4) & 7);
            const float4 cw = pts[js];
            lx = cw.x; ly = cw.y; lz = cw.z;
            if (t == 0) {
                float* o = new_xyz + ((size_t)b * NPOINT + s) * 3;
                agent_store_f32(&o[0], lx);     // write-through, fire-and-forget
                agent_store_f32(&o[1], ly);
                agent_store_f32(&o[2], lz);
                if ((s & PUBMASK) == PUBMASK) {
                    // wait ONLY this wave's stores to reach LLC, then flag
                    asm volatile("s_waitcnt vmcnt(0)" ::: "memory");
                    __hip_atomic_store(&ctr[b * CTRSTRIDE], s + 1, __ATOMIC_RELAXED,
                                       __HIP_MEMORY_SCOPE_AGENT);
                }
            }
        }
    } else {
        // ================= CONSUMER: ball query + group =================
        const int q  = blk - BATCH;
        const int b  = q / CPB;               // batch, 0..7
        const int cb = q % CPB;               // consumer block in batch, 0..30
        const float* bx = xyz + (size_t)b * NPTS * 3;

        // stage batch xyz into LDS (unswizzled)
#pragma unroll
        for (int i = 0; i < 16; ++i) {
            const int j = i * 512 + t;
            pts[j] = make_float4(bx[3 * j + 0], bx[3 * j + 1], bx[3 * j + 2], 0.0f);
        }
        __syncthreads();

        const float* prow = points + (size_t)b * NPTS * CHANC;

        for (int s = cb * 8 + w; s < NPOINT; s += BATCH * CPB) {
            // wait for center s of batch b (padded flag line, gentle poll)
            while (__hip_atomic_load(&ctr[b * CTRSTRIDE], __ATOMIC_ACQUIRE,
                                     __HIP_MEMORY_SCOPE_AGENT) <= s)
                __builtin_amdgcn_s_sleep(32);

            const int gw = b * NPOINT + s;
            const float cx = __hip_atomic_load(&new_xyz[gw * 3 + 0],
                                               __ATOMIC_RELAXED, __HIP_MEMORY_SCOPE_AGENT);
            const float cy = __hip_atomic_load(&new_xyz[gw * 3 + 1],
                                               __ATOMIC_RELAXED, __HIP_MEMORY_SCOPE_AGENT);
            const float cz = __hip_atomic_load(&new_xyz[gw * 3 + 2],
                                               __ATOMIC_RELAXED, __HIP_MEMORY_SCOPE_AGENT);

            // scan all 8192 pts from LDS, ballot-ordered first-32 collection
            int k = 0;
            for (int base = 0; base < NPTS; base += 64) {
                const float4 p = pts[base + lane];
                const float dx = p.x - cx;
                const float dy = p.y - cy;
                const float dz = p.z - cz;
                const float d2 = (dx * dx + dy * dy) + dz * dz;   // contract off
                const bool in = d2 < R2;
                const unsigned long long mu = __ballot(in);
                const int pre = __popcll(mu & ((1ull << lane) - 1ull));
                if (in && (k + pre) < NSAMPLE) idxbuf[w][k + pre] = base + lane;
                k += __popcll(mu);
                if (k >= NSAMPLE) { k = NSAMPLE; break; }
            }
            const int first = idxbuf[w][0];   // center itself => k >= 1

            // gather: 32x35 elems, coalesced stores
            float* o = out + (size_t)gw * NSAMPLE * OUTC;
            for (int e = lane; e < NSAMPLE * OUTC; e += 64) {
                const int sj = e / OUTC;
                const int c  = e - sj * OUTC;
                const int j  = (sj < k) ? idxbuf[w][sj] : first;
                float vv;
                if (c < 3) {
                    const float4 pj = pts[j];
                    const float pv = (c == 0) ? pj.x : (c == 1) ? pj.y : pj.z;
                    const float cc = (c == 0) ? cx : (c == 1) ? cy : cz;
                    vv = pv - cc;
                } else {
                    vv = prow[j * CHANC + (c - 3)];
                }
                o[e] = vv;
            }
        }
    }
}

// ---------------------------------------------------------------------------
extern "C" void kernel_launch(void* const* d_in, const int* in_sizes, int n_in,
                              void* d_out, int out_size, void* d_ws, size_t ws_size,
                              hipStream_t stream) {
    const float* xyz    = (const float*)d_in[0];   // (8, 8192, 3)  fp32
    const float* points = (const float*)d_in[1];   // (8, 8192, 32) fp32
    float* new_xyz    = (float*)d_out;                         // (8,1024,3)
    float* new_points = new_xyz + (size_t)BATCH * NPOINT * 3;  // (8,1024,32,35)
    int*   ctr        = (int*)d_ws;                            // padded flags

    hipMemsetAsync(ctr, 0, BATCH * CTRSTRIDE * sizeof(int), stream);

    void* args[] = {(void*)&xyz, (void*)&points, (void*)&new_xyz,
                    (void*)&new_points, (void*)&ctr};
    hipLaunchCooperativeKernel((const void*)fused_kernel, dim3(NBLK), dim3(512),
                               args, 0, stream);
}

// Round 19
// 1016.157 us; speedup vs baseline: 1.0312x; 1.0312x over previous
//
#include <hip/hip_runtime.h>

#define BATCH   8
#define NPTS    8192
#define NPOINT  1024
#define NSAMPLE 32
#define CHANC   32
#define OUTC    35          // 3 xyz + 32 point channels
#define R2      0.0625f     // 0.25^2
#define CPB     31          // consumer blocks per batch
#define NBLK    (BATCH + BATCH * CPB)   // 8 + 248 = 256
#define CTRSTRIDE 32        // ints per batch flag: one 128-B line each
#define PUBMASK 127         // publish every 128 centers (8/batch)

typedef float v2f __attribute__((ext_vector_type(2)));

// DPP helpers --------------------------------------------------------------
template <int CTRL>
__device__ __forceinline__ float dpp_max_step(float v) {
    int r = __builtin_amdgcn_update_dpp(__float_as_int(v), __float_as_int(v),
                                        CTRL, 0xf, 0xf, false);
    return fmaxf(v, __int_as_float(r));
}
#define DPP_ROW_SHR(n)  (0x110 | (n))
#define DPP_BCAST15     0x142
#define DPP_BCAST31     0x143

__device__ __forceinline__ unsigned long long u64max(unsigned long long a,
                                                     unsigned long long b) {
    return a > b ? a : b;
}

// ---------------------------------------------------------------------------
// Fused producer/consumer kernel, cooperative launch (256 blocks x 512 thr,
// 1 block/CU co-resident).
//  Blocks 0..7   : FROZEN r9 fps, plain coord stores (r18: write-through
//                  stores cost ~90 µs — reverted). Publish every 128 centers
//                  via agent-scope RELEASE store. The release's XCD-L2
//                  writeback is now CHEAP because consumers keep the L2
//                  clean (r17 evidence: 4.2 µs/publish == writing back the
//                  ~4 MiB of dirty consumer out-lines; nt stores fix that).
//  Blocks 8..255 : as r17, but `out` is written with NONTEMPORAL stores
//                  (bypass L2 -> no dirty lines -> cheap producer publishes;
//                  visibility guaranteed by end-of-dispatch flush).
// ---------------------------------------------------------------------------
__global__ __launch_bounds__(512) void fused_kernel(const float* __restrict__ xyz,
                                                    const float* __restrict__ points,
                                                    float* new_xyz,
                                                    float* out,
                                                    int* ctr) {
#pragma clang fp contract(off)
    __shared__ float4 pts[NPTS];                    // 128 KB
    __shared__ unsigned long long partial[2][8];
    __shared__ int idxbuf[8][NSAMPLE];              // consumer: per-wave

    const int blk  = blockIdx.x;
    const int t    = threadIdx.x;
    const int lane = t & 63;
    const int w    = t >> 6;

    if (blk < BATCH) {
        // ================= PRODUCER: fps for batch b =================
        const int b = blk;
        const float* bx = xyz + (size_t)b * NPTS * 3;

        v2f px[8], py[8], pz[8], dist[8];
        {
            float f[48];
            float4* fq = (float4*)f;
            const float4* s4 = (const float4*)bx + t * 12;
#pragma unroll
            for (int q = 0; q < 12; ++q) fq[q] = s4[q];
#pragma unroll
            for (int p = 0; p < 8; ++p) {
                px[p] = (v2f){f[6 * p + 0], f[6 * p + 3]};
                py[p] = (v2f){f[6 * p + 1], f[6 * p + 4]};
                pz[p] = (v2f){f[6 * p + 2], f[6 * p + 5]};
                dist[p] = (v2f){1e38f, 1e38f};
            }
#pragma unroll
            for (int i = 0; i < 16; ++i) {
                const int j  = t * 16 + i;
                const int js = j ^ ((j >> 4) & 7);      // bank swizzle
                pts[js] = make_float4(f[3 * i + 0], f[3 * i + 1], f[3 * i + 2], 0.0f);
            }
        }
        __syncthreads();

        float4 c0 = pts[0];
        float lx = c0.x, ly = c0.y, lz = c0.z;
        if (t == 0) {
            float* o = new_xyz + (size_t)b * NPOINT * 3;
            o[0] = lx; o[1] = ly; o[2] = lz;
        }

        for (int s = 1; s < NPOINT; ++s) {
            const v2f lx2 = (v2f){lx, lx};
            const v2f ly2 = (v2f){ly, ly};
            const v2f lz2 = (v2f){lz, lz};
            float bestv = -1.0f;
            int   bi    = 0;
#pragma unroll
            for (int p = 0; p < 8; ++p) {
                const v2f dx = px[p] - lx2;
                const v2f dy = py[p] - ly2;
                const v2f dz = pz[p] - lz2;
                const v2f d2 = (dx * dx + dy * dy) + dz * dz;   // contract off
                const float d0 = fminf(dist[p].x, d2.x);
                const float d1 = fminf(dist[p].y, d2.y);
                dist[p] = (v2f){d0, d1};
                if (d0 > bestv) { bestv = d0; bi = 2 * p; }
                if (d1 > bestv) { bestv = d1; bi = 2 * p + 1; }
            }
            const int besti = (t << 4) + bi;

            float v = bestv;
            v = dpp_max_step<DPP_ROW_SHR(1)>(v);
            v = dpp_max_step<DPP_ROW_SHR(2)>(v);
            v = dpp_max_step<DPP_ROW_SHR(4)>(v);
            v = dpp_max_step<DPP_ROW_SHR(8)>(v);
            v = dpp_max_step<DPP_BCAST15>(v);
            v = dpp_max_step<DPP_BCAST31>(v);
            const float smax = __int_as_float(__builtin_amdgcn_readlane(__float_as_int(v), 63));

            const unsigned long long m = __ballot(bestv == smax);
            const int par = s & 1;
            if (lane == (int)__builtin_ctzll(m)) {
                partial[par][w] = ((unsigned long long)__float_as_uint(smax) << 32)
                                  | (unsigned)(~besti);
            }
            __syncthreads();

            const unsigned long long* P = partial[par];
            const unsigned long long a0 = P[0], a1 = P[1], a2 = P[2], a3 = P[3];
            const unsigned long long a4 = P[4], a5 = P[5], a6 = P[6], a7 = P[7];
            const unsigned long long bp =
                u64max(u64max(u64max(a0, a1), u64max(a2, a3)),
                       u64max(u64max(a4, a5), u64max(a6, a7)));
            const int idx = (int)(~(unsigned)bp);
            const int js  = idx ^ ((idx >> 4) & 7);
            const float4 cw = pts[js];
            lx = cw.x; ly = cw.y; lz = cw.z;
            if (t == 0) {
                float* o = new_xyz + ((size_t)b * NPOINT + s) * 3;
                o[0] = lx; o[1] = ly; o[2] = lz;
                if ((s & PUBMASK) == PUBMASK) {     // publish every 128 centers
                    __hip_atomic_store(&ctr[b * CTRSTRIDE], s + 1, __ATOMIC_RELEASE,
                                       __HIP_MEMORY_SCOPE_AGENT);
                }
            }
        }
    } else {
        // ================= CONSUMER: ball query + group =================
        const int q  = blk - BATCH;
        const int b  = q / CPB;               // batch, 0..7
        const int cb = q % CPB;               // consumer block in batch, 0..30
        const float* bx = xyz + (size_t)b * NPTS * 3;

        // stage batch xyz into LDS (unswizzled)
#pragma unroll
        for (int i = 0; i < 16; ++i) {
            const int j = i * 512 + t;
            pts[j] = make_float4(bx[3 * j + 0], bx[3 * j + 1], bx[3 * j + 2], 0.0f);
        }
        __syncthreads();

        const float* prow = points + (size_t)b * NPTS * CHANC;

        for (int s = cb * 8 + w; s < NPOINT; s += BATCH * CPB) {
            // wait for center s of batch b (padded flag line, gentle poll)
            while (__hip_atomic_load(&ctr[b * CTRSTRIDE], __ATOMIC_ACQUIRE,
                                     __HIP_MEMORY_SCOPE_AGENT) <= s)
                __builtin_amdgcn_s_sleep(32);

            const int gw = b * NPOINT + s;
            const float cx = __hip_atomic_load(&new_xyz[gw * 3 + 0],
                                               __ATOMIC_RELAXED, __HIP_MEMORY_SCOPE_AGENT);
            const float cy = __hip_atomic_load(&new_xyz[gw * 3 + 1],
                                               __ATOMIC_RELAXED, __HIP_MEMORY_SCOPE_AGENT);
            const float cz = __hip_atomic_load(&new_xyz[gw * 3 + 2],
                                               __ATOMIC_RELAXED, __HIP_MEMORY_SCOPE_AGENT);

            // scan all 8192 pts from LDS, ballot-ordered first-32 collection
            int k = 0;
            for (int base = 0; base < NPTS; base += 64) {
                const float4 p = pts[base + lane];
                const float dx = p.x - cx;
                const float dy = p.y - cy;
                const float dz = p.z - cz;
                const float d2 = (dx * dx + dy * dy) + dz * dz;   // contract off
                const bool in = d2 < R2;
                const unsigned long long mu = __ballot(in);
                const int pre = __popcll(mu & ((1ull << lane) - 1ull));
                if (in && (k + pre) < NSAMPLE) idxbuf[w][k + pre] = base + lane;
                k += __popcll(mu);
                if (k >= NSAMPLE) { k = NSAMPLE; break; }
            }
            const int first = idxbuf[w][0];   // center itself => k >= 1

            // gather: 32x35 elems; NONTEMPORAL stores keep the XCD L2 clean
            // so the producer's release publish has ~nothing to write back.
            float* o = out + (size_t)gw * NSAMPLE * OUTC;
            for (int e = lane; e < NSAMPLE * OUTC; e += 64) {
                const int sj = e / OUTC;
                const int c  = e - sj * OUTC;
                const int j  = (sj < k) ? idxbuf[w][sj] : first;
                float vv;
                if (c < 3) {
                    const float4 pj = pts[j];
                    const float pv = (c == 0) ? pj.x : (c == 1) ? pj.y : pj.z;
                    const float cc = (c == 0) ? cx : (c == 1) ? cy : cz;
                    vv = pv - cc;
                } else {
                    vv = prow[j * CHANC + (c - 3)];
                }
                __builtin_nontemporal_store(vv, &o[e]);
            }
        }
    }
}

// ---------------------------------------------------------------------------
extern "C" void kernel_launch(void* const* d_in, const int* in_sizes, int n_in,
                              void* d_out, int out_size, void* d_ws, size_t ws_size,
                              hipStream_t stream) {
    const float* xyz    = (const float*)d_in[0];   // (8, 8192, 3)  fp32
    const float* points = (const float*)d_in[1];   // (8, 8192, 32) fp32
    float* new_xyz    = (float*)d_out;                         // (8,1024,3)
    float* new_points = new_xyz + (size_t)BATCH * NPOINT * 3;  // (8,1024,32,35)
    int*   ctr        = (int*)d_ws;                            // padded flags

    hipMemsetAsync(ctr, 0, BATCH * CTRSTRIDE * sizeof(int), stream);

    void* args[] = {(void*)&xyz, (void*)&points, (void*)&new_xyz,
                    (void*)&new_points, (void*)&ctr};
    hipLaunchCooperativeKernel((const void*)fused_kernel, dim3(NBLK), dim3(512),
                               args, 0, stream);
}